// Round 6
// baseline (84.908 us; speedup 1.0000x reference)
//
#include <hip/hip_runtime.h>

#define EPS_BN 1e-5f

typedef __attribute__((ext_vector_type(8))) short short8v;
typedef __attribute__((ext_vector_type(4))) float f32x4;
typedef __attribute__((ext_vector_type(4))) _Float16 h16x4;

__device__ inline unsigned short f2bf(float f) {
    union { float f; unsigned u; } v; v.f = f;
    unsigned r = v.u + 0x7fffu + ((v.u >> 16) & 1u);
    return (unsigned short)(r >> 16);
}

// ---------------------------------------------------------------------------
// Kernel P: build Web[ch128][kk*64+ci] bf16 and Wcb[oc][ci] bf16
// ---------------------------------------------------------------------------
__global__ __launch_bounds__(256) void prep_kernel(
    const float* __restrict__ w_enc, const float* __restrict__ w_comp,
    unsigned short* __restrict__ Web, unsigned short* __restrict__ Wcb)
{
    const int tid = blockIdx.x * 256 + threadIdx.x;
    const int nthr = gridDim.x * 256;
    for (int i = tid; i < 128 * 576; i += nthr) {
        int ch = i / 576;
        int r  = i - ch * 576;
        int kk = r >> 6;
        int ci = r & 63;
        float v = (ch < 100) ? w_enc[ch * 576 + ci * 9 + kk] : 0.f;
        Web[i] = f2bf(v);
    }
    for (int i = tid; i < 64 * 256; i += nthr)
        Wcb[i] = f2bf(w_comp[i]);
}

// ---------------------------------------------------------------------------
// FUSED front: 1x1 conv+BN+SiLU (MFMA, redundant halo) -> t in swizzled LDS
//              -> 3x3 conv+BN (MFMA) -> softmax -> Wl fp16.
// grid (wseg=3, h=48, b=2), block 256 (4 waves).  LDS ~14.6 KB.
// t halo: px = row*18+col, row 0..2 (image h-1+row), col 0..17 (image w0-1+col)
// tl layout: byte = (px*128 + oc*2) ^ ((px&7)<<4).
// Out-of-image halo positions must store ZERO (conv zero-padding), not BN(0).
// ---------------------------------------------------------------------------
__global__ __launch_bounds__(256) void fused_front(
    const float* __restrict__ X, const unsigned short* __restrict__ Wcb,
    const unsigned short* __restrict__ Web,
    const float* __restrict__ g1, const float* __restrict__ b1,
    const float* __restrict__ m1, const float* __restrict__ v1,
    const float* __restrict__ g2, const float* __restrict__ b2,
    const float* __restrict__ m2, const float* __restrict__ v2,
    _Float16* __restrict__ Wl)
{
    const int wseg = blockIdx.x;
    const int h = blockIdx.y;
    const int b = blockIdx.z;
    const int tid  = threadIdx.x;
    const int wave = tid >> 6;
    const int l    = tid & 63;
    const int lr   = l & 15;
    const int lk   = l >> 4;
    const int w0   = wseg * 16;

    __shared__ unsigned short tl[56 * 64];   // swizzled, 7 KB
    __shared__ float elds[16 * 116];         // 7.4 KB

    // ---- Phase 1: comp MFMA.  A-row px = wave*16+lr, 4 n-tiles (oc 0..63).
    {
        const int px  = wave * 16 + lr;
        const int row = px / 18;
        const int col = px - row * 18;
        const int hg  = h - 1 + row;
        const int wg  = w0 - 1 + col;
        const bool av = (px < 54) && ((unsigned)hg < 48u) && ((unsigned)wg < 48u);
        const float* xb = X + (size_t)b * 589824 + hg * 48 + wg;

        f32x4 acc[4] = {{0,0,0,0},{0,0,0,0},{0,0,0,0},{0,0,0,0}};
        #pragma unroll
        for (int s = 0; s < 8; ++s) {
            const int ci0 = s * 32 + lk * 8;
            short8v a;
            #pragma unroll
            for (int j = 0; j < 8; ++j)
                a[j] = av ? (short)f2bf(xb[(size_t)(ci0 + j) * 2304]) : (short)0;
            #pragma unroll
            for (int nt = 0; nt < 4; ++nt) {
                const short8v f = *(const short8v*)(Wcb + (nt*16 + lr)*256 + ci0);
                acc[nt] = __builtin_amdgcn_mfma_f32_16x16x32_bf16(a, f, acc[nt], 0, 0, 0);
            }
        }
        #pragma unroll
        for (int nt = 0; nt < 4; ++nt) {
            const int oc = nt * 16 + lr;
            const float sc = g1[oc] * rsqrtf(v1[oc] + EPS_BN);
            const float sh = b1[oc] - m1[oc] * sc;
            #pragma unroll
            for (int r = 0; r < 4; ++r) {
                const int pxo = wave * 16 + lk * 4 + r;
                if (pxo < 54) {
                    const int prow = pxo / 18;
                    const int pcol = pxo - prow * 18;
                    const int phg  = h - 1 + prow;
                    const int pwg  = w0 - 1 + pcol;
                    const bool inimg = ((unsigned)phg < 48u) && ((unsigned)pwg < 48u);
                    float v = fmaf(acc[nt][r], sc, sh);
                    float t = v / (1.f + __expf(-v));
                    const int byte = (pxo * 128 + oc * 2) ^ ((pxo & 7) << 4);
                    *(unsigned short*)((char*)tl + byte) = inimg ? f2bf(t) : (unsigned short)0;
                }
            }
        }
    }
    __syncthreads();

    // ---- Phase 2: enc MFMA from LDS t.  n-tiles nt0, nt1 per wave.
    {
        const int nt0 = wave * 2, nt1 = wave * 2 + 1;
        f32x4 acc0 = {0.f,0.f,0.f,0.f};
        f32x4 acc1 = {0.f,0.f,0.f,0.f};
        const unsigned short* wb0 = Web + (nt0*16 + lr)*576;
        const unsigned short* wb1 = Web + (nt1*16 + lr)*576;

        #pragma unroll 6
        for (int s = 0; s < 18; ++s) {
            const int kk = s >> 1;
            const int ky = (kk * 11) >> 5;
            const int kx = kk - ky * 3;
            const int cio = ((s & 1) << 5) + lk * 8;
            const int pa  = ky * 18 + lr + kx;
            const int byte = (pa * 128 + cio * 2) ^ ((pa & 7) << 4);
            const short8v a  = *(const short8v*)((char*)tl + byte);
            const short8v f0 = *(const short8v*)(wb0 + kk*64 + cio);
            const short8v f1 = *(const short8v*)(wb1 + kk*64 + cio);
            acc0 = __builtin_amdgcn_mfma_f32_16x16x32_bf16(a, f0, acc0, 0, 0, 0);
            acc1 = __builtin_amdgcn_mfma_f32_16x16x32_bf16(a, f1, acc1, 0, 0, 0);
        }

        #pragma unroll
        for (int t = 0; t < 2; ++t) {
            const int nt = t ? nt1 : nt0;
            if (nt >= 7) continue;
            const int ch = nt*16 + lr;
            float sc = 0.f, sh = 0.f;
            if (ch < 100) {
                sc = g2[ch] * rsqrtf(v2[ch] + EPS_BN);
                sh = b2[ch] - m2[ch]*sc;
            }
            const f32x4 acc = t ? acc1 : acc0;
            #pragma unroll
            for (int r = 0; r < 4; ++r)
                elds[(lk*4 + r)*116 + ch] = fmaf(acc[r], sc, sh);
        }
    }
    __syncthreads();

    // ---- Phase 3: softmax over 25 taps -> Wl fp16
    if (tid < 64) {
        const int px = tid >> 2;
        const int s  = tid & 3;
        const float* ep = &elds[px*116 + s];
        float ev[25];
        float mx = -1e30f;
        #pragma unroll
        for (int k = 0; k < 25; ++k) { ev[k] = ep[4*k]; mx = fmaxf(mx, ev[k]); }
        float sum = 0.f;
        #pragma unroll
        for (int k = 0; k < 25; ++k) { ev[k] = __expf(ev[k] - mx); sum += ev[k]; }
        const float rs = 1.f / sum;
        _Float16* wp = Wl + ((b*48 + h)*48 + w0 + px)*112 + s*28;
        #pragma unroll
        for (int k4 = 0; k4 < 6; ++k4) {
            h16x4 o = { (_Float16)(ev[k4*4+0]*rs), (_Float16)(ev[k4*4+1]*rs),
                        (_Float16)(ev[k4*4+2]*rs), (_Float16)(ev[k4*4+3]*rs) };
            *(h16x4*)(wp + k4*4) = o;
        }
        wp[24] = (_Float16)(ev[24]*rs);
    }
}

// ---------------------------------------------------------------------------
// Kernel C v4: reassembly, 16 ch/block, fp16 weights, 192 threads, ~28 KB LDS.
// grid (cg=16, h=48, b=2), block 192.
// ---------------------------------------------------------------------------
__global__ __launch_bounds__(192) void carafe_kernel(
    const float* __restrict__ X, const _Float16* __restrict__ Wl,
    float* __restrict__ out)
{
    const int cg = blockIdx.x;
    const int h = blockIdx.y;
    const int b = blockIdx.z;
    __shared__ float xl[4240];          // [(ci>>2):4][r:5][cp:53][ci&3]
    __shared__ _Float16 wrow[48*120];   // [w:48][120], 112 used
    const int tid = threadIdx.x;

    for (int idx = tid; idx < 16*265; idx += 192) {
        int ci  = idx / 265;
        int rem = idx - ci*265;
        int r   = rem / 53;
        int cp  = rem - r*53;
        int hh = h - 2 + r;
        int w  = cp - 2;
        float val = 0.f;
        if (hh >= 0 && hh < 48 && (unsigned)w < 48u)
            val = X[(b*256 + cg*16 + ci)*2304 + hh*48 + w];
        xl[(((ci>>2)*5 + r)*53 + cp)*4 + (ci&3)] = val;
    }
    {
        const unsigned* wsrc = (const unsigned*)(Wl + ((b*48 + h)*48)*112);
        for (int idx = tid; idx < 2688; idx += 192) {
            int f = idx * 2;            // half index
            int w = f / 112;
            int j = f - w*112;
            *(unsigned*)&wrow[w*120 + j] = wsrc[idx];
        }
    }
    __syncthreads();

    const int c4g = tid & 3;
    const int w   = tid >> 2;    // 0..47, all active
    {
        float4 xv[25];
        #pragma unroll
        for (int r = 0; r < 5; ++r)
            #pragma unroll
            for (int dx = 0; dx < 5; ++dx)
                xv[r*5 + dx] = *(const float4*)&xl[((c4g*5 + r)*53 + (w + dx))*4];
        const _Float16* wb = &wrow[w*120];
        #pragma unroll
        for (int s = 0; s < 4; ++s) {
            float ax=0.f, ay=0.f, az=0.f, aw=0.f;
            #pragma unroll
            for (int k4 = 0; k4 < 6; ++k4) {
                const h16x4 hv = *(const h16x4*)&wb[s*28 + k4*4];
                const float w0f = (float)hv[0], w1f = (float)hv[1];
                const float w2f = (float)hv[2], w3f = (float)hv[3];
                const float4 p0 = xv[k4*4+0], p1 = xv[k4*4+1], p2 = xv[k4*4+2], p3 = xv[k4*4+3];
                ax = fmaf(w0f,p0.x,fmaf(w1f,p1.x,fmaf(w2f,p2.x,fmaf(w3f,p3.x,ax))));
                ay = fmaf(w0f,p0.y,fmaf(w1f,p1.y,fmaf(w2f,p2.y,fmaf(w3f,p3.y,ay))));
                az = fmaf(w0f,p0.z,fmaf(w1f,p1.z,fmaf(w2f,p2.z,fmaf(w3f,p3.z,az))));
                aw = fmaf(w0f,p0.w,fmaf(w1f,p1.w,fmaf(w2f,p2.w,fmaf(w3f,p3.w,aw))));
            }
            const float wk = (float)wb[s*28 + 24];
            const float4 pl = xv[24];
            ax = fmaf(wk,pl.x,ax); ay = fmaf(wk,pl.y,ay);
            az = fmaf(wk,pl.z,az); aw = fmaf(wk,pl.w,aw);
            const int y = 2*h + (s>>1);
            const int x = 2*w + (s&1);
            float* ob = &out[((size_t)(b*256 + cg*16 + c4g*4)*96 + y)*96 + x];
            ob[0]     = ax;
            ob[9216]  = ay;
            ob[18432] = az;
            ob[27648] = aw;
        }
    }
}

extern "C" void kernel_launch(void* const* d_in, const int* in_sizes, int n_in,
                              void* d_out, int out_size, void* d_ws, size_t ws_size,
                              hipStream_t stream)
{
    (void)in_sizes; (void)n_in; (void)out_size; (void)ws_size;
    const float* X      = (const float*)d_in[0];
    const float* w_comp = (const float*)d_in[1];
    const float* g1     = (const float*)d_in[2];
    const float* b1     = (const float*)d_in[3];
    const float* m1     = (const float*)d_in[4];
    const float* v1     = (const float*)d_in[5];
    const float* w_enc  = (const float*)d_in[6];
    const float* g2     = (const float*)d_in[7];
    const float* b2     = (const float*)d_in[8];
    const float* m2     = (const float*)d_in[9];
    const float* v2     = (const float*)d_in[10];
    float* out = (float*)d_out;

    char* ws = (char*)d_ws;
    unsigned short* Web = (unsigned short*)(ws + 0);        // 147456 B
    unsigned short* Wcb = (unsigned short*)(ws + 147456);   // 32768 B
    _Float16*       Wl  = (_Float16*)(ws + 180224);         // 1032192 B

    prep_kernel<<<64, 256, 0, stream>>>(w_enc, w_comp, Web, Wcb);
    dim3 gF(3, 48, 2);
    fused_front<<<gF, 256, 0, stream>>>(X, Wcb, Web, g1, b1, m1, v1,
                                        g2, b2, m2, v2, Wl);
    dim3 gC(16, 48, 2);
    carafe_kernel<<<gC, 192, 0, stream>>>(X, Wl, out);
}

// Round 7
// 62.601 us; speedup vs baseline: 1.3563x; 1.3563x over previous
//
#include <hip/hip_runtime.h>

#define EPS_BN 1e-5f

typedef __attribute__((ext_vector_type(8))) short short8v;
typedef __attribute__((ext_vector_type(4))) float f32x4;

__device__ inline unsigned short f2bf(float f) {
    union { float f; unsigned u; } v; v.f = f;
    unsigned r = v.u + 0x7fffu + ((v.u >> 16) & 1u);
    return (unsigned short)(r >> 16);
}

// ---------------------------------------------------------------------------
// Kernel P: zero t_pad (uint4), build Web[ch128][kk*64+ci] bf16, Wcb[oc][ci] bf16
// ---------------------------------------------------------------------------
__global__ __launch_bounds__(256) void prep_kernel(
    const float* __restrict__ w_enc, const float* __restrict__ w_comp,
    uint4* __restrict__ tpad_v, unsigned short* __restrict__ Web,
    unsigned short* __restrict__ Wcb)
{
    const int tid = blockIdx.x * 256 + threadIdx.x;
    const int nthr = gridDim.x * 256;
    const uint4 z = {0u,0u,0u,0u};
    for (int i = tid; i < 40000; i += nthr)        // 2*50*50*64 bf16 = 40000 uint4
        tpad_v[i] = z;
    for (int i = tid; i < 128 * 576; i += nthr) {
        int ch = i / 576;
        int r  = i - ch * 576;
        int kk = r >> 6;
        int ci = r & 63;
        float v = (ch < 100) ? w_enc[ch * 576 + ci * 9 + kk] : 0.f;
        Web[i] = f2bf(v);
    }
    for (int i = tid; i < 64 * 256; i += nthr)
        Wcb[i] = f2bf(w_comp[i]);
}

// ---------------------------------------------------------------------------
// Kernel A (R4): 1x1 conv (256->64) via MFMA bf16 + BN + SiLU -> tpad bf16.
// grid (wseg=3, h=48, b=2), block 256.
// ---------------------------------------------------------------------------
__global__ __launch_bounds__(256) void comp_mfma(
    const float* __restrict__ X, const unsigned short* __restrict__ Wcb,
    const float* __restrict__ g1, const float* __restrict__ b1,
    const float* __restrict__ m1, const float* __restrict__ v1,
    unsigned short* __restrict__ tpad)
{
    const int wseg = blockIdx.x;
    const int h = blockIdx.y;
    const int b = blockIdx.z;
    const int tid  = threadIdx.x;
    const int wave = tid >> 6;
    const int l    = tid & 63;
    const int lr   = l & 15;
    const int lk   = l >> 4;
    const int w0   = wseg * 16;

    f32x4 acc = {0.f,0.f,0.f,0.f};
    const float* xb = X + (size_t)b * 589824 + h * 48 + w0 + lr;
    const unsigned short* wb = Wcb + (wave * 16 + lr) * 256;

    #pragma unroll
    for (int s = 0; s < 8; ++s) {
        const int ci0 = s * 32 + lk * 8;
        short8v a;
        #pragma unroll
        for (int j = 0; j < 8; ++j)
            a[j] = (short)f2bf(xb[(size_t)(ci0 + j) * 2304]);
        const short8v f = *(const short8v*)(wb + ci0);
        acc = __builtin_amdgcn_mfma_f32_16x16x32_bf16(a, f, acc, 0, 0, 0);
    }

    const int oc = wave * 16 + lr;
    const float sc = g1[oc] * rsqrtf(v1[oc] + EPS_BN);
    const float sh = b1[oc] - m1[oc] * sc;
    unsigned short* tp = tpad + ((b*50 + h + 1)*50 + 1)*64 + oc;
    #pragma unroll
    for (int r = 0; r < 4; ++r) {
        float v = fmaf(acc[r], sc, sh);
        float t = v / (1.f + __expf(-v));          // SiLU
        tp[(w0 + lk*4 + r)*64] = f2bf(t);
    }
}

// ---------------------------------------------------------------------------
// Kernel B (R4): 3x3 conv (64->100) MFMA + BN + fused softmax -> Wl fp32.
// grid (wseg=3, h=48, b=2), block 256 (4 waves).
// ---------------------------------------------------------------------------
__global__ __launch_bounds__(256) void enc_sm(
    const unsigned short* __restrict__ tpad, const unsigned short* __restrict__ Web,
    const float* __restrict__ g2, const float* __restrict__ b2,
    const float* __restrict__ m2, const float* __restrict__ v2,
    float* __restrict__ Wl)
{
    const int wseg = blockIdx.x;
    const int h = blockIdx.y;
    const int b = blockIdx.z;
    const int tid  = threadIdx.x;
    const int wave = tid >> 6;
    const int l    = tid & 63;
    const int lr   = l & 15;
    const int lk   = l >> 4;
    const int w0   = wseg * 16;
    const int nt0  = wave * 2, nt1 = wave * 2 + 1;
    __shared__ float elds[16 * 116];

    f32x4 acc0 = {0.f,0.f,0.f,0.f};
    f32x4 acc1 = {0.f,0.f,0.f,0.f};

    const unsigned short* tb = tpad + (b*50 + h)*50*64;
    const unsigned short* wb0 = Web + (nt0*16 + lr)*576;
    const unsigned short* wb1 = Web + (nt1*16 + lr)*576;

    #pragma unroll 6
    for (int s = 0; s < 18; ++s) {
        const int kk = s >> 1;
        const int ky = (kk * 11) >> 5;
        const int kx = kk - ky * 3;
        const int cio = ((s & 1) << 5) + lk * 8;
        const short8v a  = *(const short8v*)(tb + (ky*50 + w0 + kx + lr)*64 + cio);
        const short8v f0 = *(const short8v*)(wb0 + kk*64 + cio);
        const short8v f1 = *(const short8v*)(wb1 + kk*64 + cio);
        acc0 = __builtin_amdgcn_mfma_f32_16x16x32_bf16(a, f0, acc0, 0, 0, 0);
        acc1 = __builtin_amdgcn_mfma_f32_16x16x32_bf16(a, f1, acc1, 0, 0, 0);
    }

    #pragma unroll
    for (int t = 0; t < 2; ++t) {
        const int nt = t ? nt1 : nt0;
        if (nt >= 7) continue;
        const int ch = nt*16 + lr;
        float sc = 0.f, sh = 0.f;
        if (ch < 100) {
            sc = g2[ch] * rsqrtf(v2[ch] + EPS_BN);
            sh = b2[ch] - m2[ch]*sc;
        }
        const f32x4 acc = t ? acc1 : acc0;
        #pragma unroll
        for (int r = 0; r < 4; ++r)
            elds[(lk*4 + r)*116 + ch] = fmaf(acc[r], sc, sh);
    }
    __syncthreads();

    if (tid < 64) {
        const int px = tid >> 2;
        const int s  = tid & 3;
        const float* ep = &elds[px*116 + s];
        float ev[25];
        float mx = -1e30f;
        #pragma unroll
        for (int k = 0; k < 25; ++k) { ev[k] = ep[4*k]; mx = fmaxf(mx, ev[k]); }
        float sum = 0.f;
        #pragma unroll
        for (int k = 0; k < 25; ++k) { ev[k] = __expf(ev[k] - mx); sum += ev[k]; }
        const float rs = 1.f / sum;
        float* wp = Wl + ((b*48 + h)*48 + w0 + px)*112 + s*28;
        #pragma unroll
        for (int k4 = 0; k4 < 6; ++k4) {
            float4 o = { ev[k4*4+0]*rs, ev[k4*4+1]*rs, ev[k4*4+2]*rs, ev[k4*4+3]*rs };
            *(float4*)(wp + k4*4) = o;
        }
        wp[24] = ev[24]*rs;
    }
}

// ---------------------------------------------------------------------------
// Kernel C v5: reassembly. Block = (32 ch, h, b); computes BOTH y=2h, 2h+1
// (they share the same 5 X tap-rows).  grid (8, 48, 2) = 768 blocks, 256 thr.
// LDS: xt[32][5][52] c-stride 266 (2-way bank alias only) + wt[48][116] fp32
//  = 56.3 KB -> 2 blocks/CU.
// Lane: c = l&31, wg = wave*2+(l>>5) -> 6 consecutive w; weight f4 reads are
// 2-address broadcasts; 50 taps in regs; 6 coalesced f4 stores.
// ---------------------------------------------------------------------------
__global__ __launch_bounds__(256) void carafe_v5(
    const float* __restrict__ X, const float* __restrict__ Wl,
    float* __restrict__ out)
{
    const int cg = blockIdx.x;   // 8 groups of 32 channels
    const int h  = blockIdx.y;
    const int b  = blockIdx.z;
    __shared__ float xt[32 * 266];   // [c][r:5*52 within 266][col 52], off +2
    __shared__ float wt[48 * 116];   // [w][112 used]
    const int tid = threadIdx.x;

    // stage X: 32ch x 5 rows x 12 f4 (cols 2..49); borders 0,1,50,51 zeroed
    for (int idx = tid; idx < 1920; idx += 256) {
        const int ci  = idx / 60;
        const int rem = idx - ci * 60;
        const int r   = rem / 12;
        const int q   = rem - r * 12;
        const int hh  = h - 2 + r;
        float4 v = {0.f,0.f,0.f,0.f};
        if ((unsigned)hh < 48u)
            v = *(const float4*)&X[(size_t)(b*256 + cg*32 + ci)*2304 + hh*48 + q*4];
        float* dst = &xt[ci*266 + r*52 + 2 + q*4];
        *(float2*)dst       = make_float2(v.x, v.y);
        *(float2*)(dst + 2) = make_float2(v.z, v.w);
    }
    for (int idx = tid; idx < 320; idx += 256) {
        const int ci   = idx / 10;
        const int rem  = idx - ci * 10;
        const int r    = rem >> 1;
        const int side = rem & 1;
        float* dst = &xt[ci*266 + r*52 + side*50];
        *(float2*)dst = make_float2(0.f, 0.f);
    }
    // stage weights fp32: 48 w-rows x 28 f4
    {
        const float* wsrc = &Wl[(size_t)((b*48 + h)*48)*112];
        for (int idx = tid; idx < 1344; idx += 256) {
            const int w = idx / 28;
            const int q = idx - w * 28;
            *(float4*)&wt[w*116 + q*4] = *(const float4*)&wsrc[w*112 + q*4];
        }
    }
    __syncthreads();

    const int wave = tid >> 6;
    const int l    = tid & 63;
    const int c    = l & 31;
    const int wg   = wave * 2 + (l >> 5);   // 0..7
    const int w0   = wg * 6;

    // taps: xr[ky][j], j=0..9 covers image w' = w0-2 .. w0+7
    float xr[5][10];
    #pragma unroll
    for (int ky = 0; ky < 5; ++ky) {
        const float* rb = &xt[c*266 + ky*52 + w0];
        #pragma unroll
        for (int i = 0; i < 5; ++i) {
            const float2 p = *(const float2*)(rb + i*2);
            xr[ky][i*2]   = p.x;
            xr[ky][i*2+1] = p.y;
        }
    }

    float acc[2][12];
    #pragma unroll
    for (int jw = 0; jw < 6; ++jw) {
        const float* wb = &wt[(w0 + jw) * 116];
        #pragma unroll
        for (int s = 0; s < 4; ++s) {
            float a = 0.f;
            #pragma unroll
            for (int k4 = 0; k4 < 6; ++k4) {
                const float4 wv = *(const float4*)&wb[s*28 + k4*4];
                #pragma unroll
                for (int j = 0; j < 4; ++j) {
                    const int k  = k4*4 + j;
                    const int ky = k / 5;
                    const int kx = k - ky*5;
                    const float wj = (j==0)?wv.x:(j==1)?wv.y:(j==2)?wv.z:wv.w;
                    a = fmaf(wj, xr[ky][jw + kx], a);
                }
            }
            a = fmaf(wb[s*28 + 24], xr[4][jw + 4], a);
            acc[s>>1][jw*2 + (s&1)] = a;
        }
    }

    #pragma unroll
    for (int sy = 0; sy < 2; ++sy) {
        const int y = 2*h + sy;
        float* ob = &out[((size_t)(b*256 + cg*32 + c)*96 + y)*96 + 2*w0];
        #pragma unroll
        for (int g = 0; g < 3; ++g) {
            float4 o = { acc[sy][g*4], acc[sy][g*4+1], acc[sy][g*4+2], acc[sy][g*4+3] };
            *(float4*)(ob + g*4) = o;
        }
    }
}

extern "C" void kernel_launch(void* const* d_in, const int* in_sizes, int n_in,
                              void* d_out, int out_size, void* d_ws, size_t ws_size,
                              hipStream_t stream)
{
    (void)in_sizes; (void)n_in; (void)out_size; (void)ws_size;
    const float* X      = (const float*)d_in[0];
    const float* w_comp = (const float*)d_in[1];
    const float* g1     = (const float*)d_in[2];
    const float* b1     = (const float*)d_in[3];
    const float* m1     = (const float*)d_in[4];
    const float* v1     = (const float*)d_in[5];
    const float* w_enc  = (const float*)d_in[6];
    const float* g2     = (const float*)d_in[7];
    const float* b2     = (const float*)d_in[8];
    const float* m2     = (const float*)d_in[9];
    const float* v2     = (const float*)d_in[10];
    float* out = (float*)d_out;

    char* ws = (char*)d_ws;
    unsigned short* tpad = (unsigned short*)(ws + 0);        // 640000 B
    unsigned short* Web  = (unsigned short*)(ws + 640000);   // 147456 B
    unsigned short* Wcb  = (unsigned short*)(ws + 787456);   // 32768 B
    float*          Wl   = (float*)(ws + 820224);            // 2064384 B

    prep_kernel<<<128, 256, 0, stream>>>(w_enc, w_comp, (uint4*)tpad, Web, Wcb);
    dim3 gA(3, 48, 2);
    comp_mfma<<<gA, 256, 0, stream>>>(X, Wcb, g1, b1, m1, v1, tpad);
    dim3 gB(3, 48, 2);
    enc_sm<<<gB, 256, 0, stream>>>(tpad, Web, g2, b2, m2, v2, Wl);
    dim3 gC(8, 48, 2);
    carafe_v5<<<gC, 256, 0, stream>>>(X, Wl, out);
}

// Round 8
// 46.225 us; speedup vs baseline: 1.8368x; 1.3543x over previous
//
#include <hip/hip_runtime.h>

#define EPS_BN 1e-5f

typedef __attribute__((ext_vector_type(8))) short short8v;
typedef __attribute__((ext_vector_type(4))) float f32x4;

__device__ inline unsigned short f2bf(float f) {
    union { float f; unsigned u; } v; v.f = f;
    unsigned r = v.u + 0x7fffu + ((v.u >> 16) & 1u);
    return (unsigned short)(r >> 16);
}

// ---------------------------------------------------------------------------
// Kernel P: zero t_pad (uint4), build Web[ch128][kk*64+ci] bf16, Wcb[oc][ci] bf16
// ---------------------------------------------------------------------------
__global__ __launch_bounds__(256) void prep_kernel(
    const float* __restrict__ w_enc, const float* __restrict__ w_comp,
    uint4* __restrict__ tpad_v, unsigned short* __restrict__ Web,
    unsigned short* __restrict__ Wcb)
{
    const int tid = blockIdx.x * 256 + threadIdx.x;
    const int nthr = gridDim.x * 256;
    const uint4 z = {0u,0u,0u,0u};
    for (int i = tid; i < 40000; i += nthr)        // 2*50*50*64 bf16 = 40000 uint4
        tpad_v[i] = z;
    for (int i = tid; i < 128 * 576; i += nthr) {
        int ch = i / 576;
        int r  = i - ch * 576;
        int kk = r >> 6;
        int ci = r & 63;
        float v = (ch < 100) ? w_enc[ch * 576 + ci * 9 + kk] : 0.f;
        Web[i] = f2bf(v);
    }
    for (int i = tid; i < 64 * 256; i += nthr)
        Wcb[i] = f2bf(w_comp[i]);
}

// ---------------------------------------------------------------------------
// Kernel A (R4): 1x1 conv (256->64) via MFMA bf16 + BN + SiLU -> tpad bf16.
// grid (wseg=3, h=48, b=2), block 256.
// ---------------------------------------------------------------------------
__global__ __launch_bounds__(256) void comp_mfma(
    const float* __restrict__ X, const unsigned short* __restrict__ Wcb,
    const float* __restrict__ g1, const float* __restrict__ b1,
    const float* __restrict__ m1, const float* __restrict__ v1,
    unsigned short* __restrict__ tpad)
{
    const int wseg = blockIdx.x;
    const int h = blockIdx.y;
    const int b = blockIdx.z;
    const int tid  = threadIdx.x;
    const int wave = tid >> 6;
    const int l    = tid & 63;
    const int lr   = l & 15;
    const int lk   = l >> 4;
    const int w0   = wseg * 16;

    f32x4 acc = {0.f,0.f,0.f,0.f};
    const float* xb = X + (size_t)b * 589824 + h * 48 + w0 + lr;
    const unsigned short* wb = Wcb + (wave * 16 + lr) * 256;

    #pragma unroll
    for (int s = 0; s < 8; ++s) {
        const int ci0 = s * 32 + lk * 8;
        short8v a;
        #pragma unroll
        for (int j = 0; j < 8; ++j)
            a[j] = (short)f2bf(xb[(size_t)(ci0 + j) * 2304]);
        const short8v f = *(const short8v*)(wb + ci0);
        acc = __builtin_amdgcn_mfma_f32_16x16x32_bf16(a, f, acc, 0, 0, 0);
    }

    const int oc = wave * 16 + lr;
    const float sc = g1[oc] * rsqrtf(v1[oc] + EPS_BN);
    const float sh = b1[oc] - m1[oc] * sc;
    unsigned short* tp = tpad + ((b*50 + h + 1)*50 + 1)*64 + oc;
    #pragma unroll
    for (int r = 0; r < 4; ++r) {
        float v = fmaf(acc[r], sc, sh);
        float t = v / (1.f + __expf(-v));          // SiLU
        tp[(w0 + lk*4 + r)*64] = f2bf(t);
    }
}

// ---------------------------------------------------------------------------
// Kernel B (R4): 3x3 conv (64->100) MFMA + BN + fused softmax -> Wl fp32.
// grid (wseg=3, h=48, b=2), block 256 (4 waves).
// ---------------------------------------------------------------------------
__global__ __launch_bounds__(256) void enc_sm(
    const unsigned short* __restrict__ tpad, const unsigned short* __restrict__ Web,
    const float* __restrict__ g2, const float* __restrict__ b2,
    const float* __restrict__ m2, const float* __restrict__ v2,
    float* __restrict__ Wl)
{
    const int wseg = blockIdx.x;
    const int h = blockIdx.y;
    const int b = blockIdx.z;
    const int tid  = threadIdx.x;
    const int wave = tid >> 6;
    const int l    = tid & 63;
    const int lr   = l & 15;
    const int lk   = l >> 4;
    const int w0   = wseg * 16;
    const int nt0  = wave * 2, nt1 = wave * 2 + 1;
    __shared__ float elds[16 * 116];

    f32x4 acc0 = {0.f,0.f,0.f,0.f};
    f32x4 acc1 = {0.f,0.f,0.f,0.f};

    const unsigned short* tb = tpad + (b*50 + h)*50*64;
    const unsigned short* wb0 = Web + (nt0*16 + lr)*576;
    const unsigned short* wb1 = Web + (nt1*16 + lr)*576;

    #pragma unroll 6
    for (int s = 0; s < 18; ++s) {
        const int kk = s >> 1;
        const int ky = (kk * 11) >> 5;
        const int kx = kk - ky * 3;
        const int cio = ((s & 1) << 5) + lk * 8;
        const short8v a  = *(const short8v*)(tb + (ky*50 + w0 + kx + lr)*64 + cio);
        const short8v f0 = *(const short8v*)(wb0 + kk*64 + cio);
        const short8v f1 = *(const short8v*)(wb1 + kk*64 + cio);
        acc0 = __builtin_amdgcn_mfma_f32_16x16x32_bf16(a, f0, acc0, 0, 0, 0);
        acc1 = __builtin_amdgcn_mfma_f32_16x16x32_bf16(a, f1, acc1, 0, 0, 0);
    }

    #pragma unroll
    for (int t = 0; t < 2; ++t) {
        const int nt = t ? nt1 : nt0;
        if (nt >= 7) continue;
        const int ch = nt*16 + lr;
        float sc = 0.f, sh = 0.f;
        if (ch < 100) {
            sc = g2[ch] * rsqrtf(v2[ch] + EPS_BN);
            sh = b2[ch] - m2[ch]*sc;
        }
        const f32x4 acc = t ? acc1 : acc0;
        #pragma unroll
        for (int r = 0; r < 4; ++r)
            elds[(lk*4 + r)*116 + ch] = fmaf(acc[r], sc, sh);
    }
    __syncthreads();

    if (tid < 64) {
        const int px = tid >> 2;
        const int s  = tid & 3;
        const float* ep = &elds[px*116 + s];
        float ev[25];
        float mx = -1e30f;
        #pragma unroll
        for (int k = 0; k < 25; ++k) { ev[k] = ep[4*k]; mx = fmaxf(mx, ev[k]); }
        float sum = 0.f;
        #pragma unroll
        for (int k = 0; k < 25; ++k) { ev[k] = __expf(ev[k] - mx); sum += ev[k]; }
        const float rs = 1.f / sum;
        float* wp = Wl + ((b*48 + h)*48 + w0 + px)*112 + s*28;
        #pragma unroll
        for (int k4 = 0; k4 < 6; ++k4) {
            float4 o = { ev[k4*4+0]*rs, ev[k4*4+1]*rs, ev[k4*4+2]*rs, ev[k4*4+3]*rs };
            *(float4*)(wp + k4*4) = o;
        }
        wp[24] = ev[24]*rs;
    }
}

// ---------------------------------------------------------------------------
// Kernel C v6: v3 structure, but weights read DIRECT from global (L2, 4-lane
// broadcast, 28 aligned float4/lane) -- no weight staging.  X stage vectorized
// (f4 global + 4x b32 LDS scatter).  LDS = 16.9 KB (xl only).
// grid (cg=16, h=48, b=2) = 1536 blocks, block 256.
// Lane: c4g = tid&3 (4 ch), w = tid>>2 (48 active of 64).
// ---------------------------------------------------------------------------
__global__ __launch_bounds__(256) void carafe_v6(
    const float* __restrict__ X, const float* __restrict__ Wl,
    float* __restrict__ out)
{
    const int cg = blockIdx.x;
    const int h = blockIdx.y;
    const int b = blockIdx.z;
    __shared__ float xl[4240];    // [(ci>>2):4][r:5][cp:53][ci&3]
    const int tid = threadIdx.x;

    // stage X: 16 ch x 5 rows x 12 f4 (cols 2..49 of cp) + border zeros
    for (int idx = tid; idx < 960; idx += 256) {
        const int ci  = idx / 60;
        const int rem = idx - ci * 60;
        const int r   = rem / 12;
        const int q   = rem - r * 12;
        const int hh  = h - 2 + r;
        float4 v = {0.f,0.f,0.f,0.f};
        if ((unsigned)hh < 48u)
            v = *(const float4*)&X[(size_t)(b*256 + cg*16 + ci)*2304 + hh*48 + q*4];
        float* base = &xl[(((ci>>2)*5 + r)*53 + 2 + q*4)*4 + (ci&3)];
        base[0]  = v.x;
        base[4]  = v.y;
        base[8]  = v.z;
        base[12] = v.w;
    }
    for (int idx = tid; idx < 320; idx += 256) {
        const int ci  = idx / 20;
        const int rem = idx - ci * 20;
        const int r   = rem / 4;
        const int e   = rem & 3;            // border cp: 0,1,50,51
        const int cp  = (e < 2) ? e : 48 + e;
        xl[(((ci>>2)*5 + r)*53 + cp)*4 + (ci&3)] = 0.f;
    }
    __syncthreads();

    const int c4g = tid & 3;
    const int w   = tid >> 2;    // 0..63, active < 48
    if (w < 48) {
        float4 xv[25];
        #pragma unroll
        for (int r = 0; r < 5; ++r)
            #pragma unroll
            for (int dx = 0; dx < 5; ++dx)
                xv[r*5 + dx] = *(const float4*)&xl[((c4g*5 + r)*53 + (w + dx))*4];
        const float* wb = &Wl[(size_t)((b*48 + h)*48 + w)*112];   // global, L2
        #pragma unroll
        for (int s = 0; s < 4; ++s) {
            float ax=0.f, ay=0.f, az=0.f, aw=0.f;
            #pragma unroll
            for (int k4 = 0; k4 < 6; ++k4) {
                const float4 wv = *(const float4*)&wb[s*28 + k4*4];
                const float4 p0 = xv[k4*4+0], p1 = xv[k4*4+1], p2 = xv[k4*4+2], p3 = xv[k4*4+3];
                ax = fmaf(wv.x,p0.x,fmaf(wv.y,p1.x,fmaf(wv.z,p2.x,fmaf(wv.w,p3.x,ax))));
                ay = fmaf(wv.x,p0.y,fmaf(wv.y,p1.y,fmaf(wv.z,p2.y,fmaf(wv.w,p3.y,ay))));
                az = fmaf(wv.x,p0.z,fmaf(wv.y,p1.z,fmaf(wv.z,p2.z,fmaf(wv.w,p3.z,az))));
                aw = fmaf(wv.x,p0.w,fmaf(wv.y,p1.w,fmaf(wv.z,p2.w,fmaf(wv.w,p3.w,aw))));
            }
            const float wk = wb[s*28 + 24];
            const float4 pl = xv[24];
            ax = fmaf(wk,pl.x,ax); ay = fmaf(wk,pl.y,ay);
            az = fmaf(wk,pl.z,az); aw = fmaf(wk,pl.w,aw);
            const int y = 2*h + (s>>1);
            const int x = 2*w + (s&1);
            float* ob = &out[((size_t)(b*256 + cg*16 + c4g*4)*96 + y)*96 + x];
            ob[0]     = ax;
            ob[9216]  = ay;
            ob[18432] = az;
            ob[27648] = aw;
        }
    }
}

extern "C" void kernel_launch(void* const* d_in, const int* in_sizes, int n_in,
                              void* d_out, int out_size, void* d_ws, size_t ws_size,
                              hipStream_t stream)
{
    (void)in_sizes; (void)n_in; (void)out_size; (void)ws_size;
    const float* X      = (const float*)d_in[0];
    const float* w_comp = (const float*)d_in[1];
    const float* g1     = (const float*)d_in[2];
    const float* b1     = (const float*)d_in[3];
    const float* m1     = (const float*)d_in[4];
    const float* v1     = (const float*)d_in[5];
    const float* w_enc  = (const float*)d_in[6];
    const float* g2     = (const float*)d_in[7];
    const float* b2     = (const float*)d_in[8];
    const float* m2     = (const float*)d_in[9];
    const float* v2     = (const float*)d_in[10];
    float* out = (float*)d_out;

    char* ws = (char*)d_ws;
    unsigned short* tpad = (unsigned short*)(ws + 0);        // 640000 B
    unsigned short* Web  = (unsigned short*)(ws + 640000);   // 147456 B
    unsigned short* Wcb  = (unsigned short*)(ws + 787456);   // 32768 B
    float*          Wl   = (float*)(ws + 820224);            // 2064384 B

    prep_kernel<<<128, 256, 0, stream>>>(w_enc, w_comp, (uint4*)tpad, Web, Wcb);
    dim3 gA(3, 48, 2);
    comp_mfma<<<gA, 256, 0, stream>>>(X, Wcb, g1, b1, m1, v1, tpad);
    dim3 gB(3, 48, 2);
    enc_sm<<<gB, 256, 0, stream>>>(tpad, Web, g2, b2, m2, v2, Wl);
    dim3 gC(16, 48, 2);
    carafe_v6<<<gC, 256, 0, stream>>>(X, Wl, out);
}